// Round 12
// baseline (988.819 us; speedup 1.0000x reference)
//
#include <hip/hip_runtime.h>
#include <hip/hip_fp16.h>

#define EMB 64
#define BSH 7                       // rows per bucket = 128
#define BROWS (1 << BSH)
#define NBMAX 4096                  // LDS hist capacity

// Packed edge: (col << 13) | q, where val = q / 81920.0  (val in [0,0.1) per spec)
typedef unsigned int PEdge;
#define VAL_SCALE 81920.0f
#define VAL_INV   (1.0f / 81920.0f)

template <typename T>
__device__ __forceinline__ T ntload(const T* p) { return __builtin_nontemporal_load(p); }

// ---------- convert fp32 concat(ue,ie) -> fp16 x buffer ----------
__global__ void k_cvt(const float4* __restrict__ ue, const float4* __restrict__ ie,
                      __half2* __restrict__ xh2, long nu4, long ni4) {
    long total = nu4 + ni4;
    long stride = (long)gridDim.x * blockDim.x;
    for (long i = (long)blockIdx.x * blockDim.x + threadIdx.x; i < total; i += stride) {
        float4 v = (i < nu4) ? ue[i] : ie[i - nu4];
        xh2[i * 2]     = __floats2half2_rn(v.x, v.y);
        xh2[i * 2 + 1] = __floats2half2_rn(v.z, v.w);
    }
}

// ---------- bucket build pass A1: LDS-privatized bucket histogram ----------
__global__ void k_bhist(const int* __restrict__ rows, int* __restrict__ bhist,
                        int ne, int nbuck) {
    __shared__ int h[NBMAX];
    for (int i = threadIdx.x; i < nbuck; i += blockDim.x) h[i] = 0;
    __syncthreads();
    int stride = gridDim.x * blockDim.x;
    for (int e = blockIdx.x * blockDim.x + threadIdx.x; e < ne; e += stride)
        atomicAdd(&h[ntload(rows + e) >> BSH], 1);
    __syncthreads();
    for (int i = threadIdx.x; i < nbuck; i += blockDim.x)
        if (h[i]) atomicAdd(&bhist[i], h[i]);
}

// ---------- pass A2: scan bucket counts -> bstart, bcursor ----------
__global__ void k_bscan(const int* __restrict__ bhist, int* __restrict__ bstart,
                        int* __restrict__ bcursor, int nbuck) {
    __shared__ int sh[256];
    int t = threadIdx.x;
    int ept = (nbuck + 255) / 256;
    int base = t * ept;
    int ts = 0;
    for (int k = 0; k < ept; ++k) if (base + k < nbuck) ts += bhist[base + k];
    sh[t] = ts;
    __syncthreads();
    for (int off = 1; off < 256; off <<= 1) {
        int x = (t >= off) ? sh[t - off] : 0;
        __syncthreads();
        sh[t] += x;
        __syncthreads();
    }
    int run = sh[t] - ts;
    for (int k = 0; k < ept; ++k) {
        if (base + k < nbuck) {
            bstart[base + k] = run;
            bcursor[base + k] = run;
            run += bhist[base + k];
        }
    }
}

// ---------- pass A3: XCD-sharded bucket scatter of 8B records ----------
// Bucket b owned by shard group (b>>4)&7: each 64B cursor line AND each bucket's
// record region has a single writer XCD; bucket writes advance sequentially via
// the cursor -> ~1 active dirty line per bucket -> full L2 write merging.
__global__ void k_bscatter(const int* __restrict__ rows, const int* __restrict__ cols,
                           const float* __restrict__ vals, int* __restrict__ bcursor,
                           unsigned long long* __restrict__ breg, int ne) {
    int g  = blockIdx.x & 7;
    int lt = (blockIdx.x >> 3) * blockDim.x + threadIdx.x;
    int gs = (gridDim.x >> 3) * blockDim.x;
    for (int e = lt; e < ne; e += gs) {
        int r = ntload(rows + e);
        int b = r >> BSH;
        if (((b >> 4) & 7) == g) {
            int p = atomicAdd(&bcursor[b], 1);
            unsigned q = (unsigned)(ntload(vals + e) * VAL_SCALE + 0.5f);
            if (q > 8191u) q = 8191u;
            unsigned lo = ((unsigned)ntload(cols + e) << 13) | q;
            breg[p] = ((unsigned long long)(unsigned)(r & (BROWS - 1)) << 32) | lo;
        }
    }
}

// ---------- pass B: per-bucket finalize -> exact CSR (pe) + row_start ----------
__global__ void k_bfinal(const unsigned long long* __restrict__ breg,
                         const int* __restrict__ bstart, PEdge* __restrict__ pe,
                         int* __restrict__ row_start, int n, int ne, int nbuck) {
    __shared__ int cnt[BROWS];
    __shared__ int off[BROWS];
    __shared__ int cur[BROWS];
    int b = blockIdx.x;
    if (b >= nbuck) return;
    int s = bstart[b];
    int e = (b + 1 < nbuck) ? bstart[b + 1] : ne;
    int t = threadIdx.x;
    if (t < BROWS) cnt[t] = 0;
    __syncthreads();
    for (int j = s + t; j < e; j += blockDim.x)
        atomicAdd(&cnt[(int)(breg[j] >> 32)], 1);
    __syncthreads();
    if (t < BROWS) off[t] = cnt[t];
    __syncthreads();
    for (int o = 1; o < BROWS; o <<= 1) {
        int x = (t >= o && t < BROWS) ? off[t - o] : 0;
        __syncthreads();
        if (t < BROWS) off[t] += x;
        __syncthreads();
    }
    if (t < BROWS) {
        int excl = off[t] - cnt[t];
        cur[t] = excl;
        int gr = (b << BSH) + t;
        if (gr < n) row_start[gr] = s + excl;
    }
    __syncthreads();
    for (int j = s + t; j < e; j += blockDim.x) {
        unsigned long long rec = breg[j];
        int rl = (int)(rec >> 32);
        int p = atomicAdd(&cur[rl], 1);
        pe[s + p] = (PEdge)(rec & 0xffffffffu);
    }
    if (b == 0 && t == 0) row_start[n] = ne;
}

// ---------- SpMM mid layer: gather fp16 (cached), write fp16 nxt (nt store) ----------
__global__ void k_spmm_mid(const int* __restrict__ row_start, const PEdge* __restrict__ pe,
                           const __half* __restrict__ x, __half* __restrict__ nxt, int n) {
    int wid = (int)(((long)blockIdx.x * blockDim.x + threadIdx.x) >> 6);
    int lane = threadIdx.x & 63;
    if (wid >= n) return;
    int s = row_start[wid];
    int e = row_start[wid + 1];
    float sum = 0.f;
    for (int j = s; j < e; j += 8) {
        int   cc[8];
        float vv[8];
#pragma unroll
        for (int k = 0; k < 8; ++k) {
            int jj = j + k;
            unsigned u = pe[jj < e ? jj : e - 1];
            cc[k] = (int)(u >> 13);
            vv[k] = (jj < e) ? (float)(u & 8191u) * VAL_INV : 0.f;
        }
        float xs[8];
#pragma unroll
        for (int k = 0; k < 8; ++k)
            xs[k] = __half2float(x[(size_t)cc[k] * EMB + lane]);
#pragma unroll
        for (int k = 0; k < 8; ++k) sum += vv[k] * xs[k];
    }
    size_t o = (size_t)wid * EMB + lane;
    short hs = __half_as_short(__float2half(sum));
    __builtin_nontemporal_store(hs, (short*)nxt + o);
}

// ---------- SpMM last layer: gather from x2 (=e2), combine all 4 layers ----------
__global__ void k_spmm_last(const int* __restrict__ row_start, const PEdge* __restrict__ pe,
                            const __half* __restrict__ x2, const __half* __restrict__ xh1,
                            const float* __restrict__ ue, const float* __restrict__ ie, int nu,
                            float* __restrict__ acc, int n) {
    int wid = (int)(((long)blockIdx.x * blockDim.x + threadIdx.x) >> 6);
    int lane = threadIdx.x & 63;
    if (wid >= n) return;
    int s = row_start[wid];
    int e = row_start[wid + 1];
    float sum = 0.f;
    for (int j = s; j < e; j += 8) {
        int   cc[8];
        float vv[8];
#pragma unroll
        for (int k = 0; k < 8; ++k) {
            int jj = j + k;
            unsigned u = pe[jj < e ? jj : e - 1];
            cc[k] = (int)(u >> 13);
            vv[k] = (jj < e) ? (float)(u & 8191u) * VAL_INV : 0.f;
        }
        float xs[8];
#pragma unroll
        for (int k = 0; k < 8; ++k)
            xs[k] = __half2float(x2[(size_t)cc[k] * EMB + lane]);
#pragma unroll
        for (int k = 0; k < 8; ++k) sum += vv[k] * xs[k];
    }
    size_t o = (size_t)wid * EMB + lane;
    const float* p = (wid < nu) ? (ue + (size_t)wid * EMB) : (ie + (size_t)(wid - nu) * EMB);
    float e0 = p[lane];
    float e1 = __half2float(xh1[o]);
    float e2 = __half2float(x2[o]);
    float r = (e0 + e1 + e2 + sum) * 0.25f;
    __builtin_nontemporal_store(r, acc + o);
}

// ---------- fallback (R1 atomic path, fp32) ----------
__global__ void lgcn_init(const float4* __restrict__ ue, const float4* __restrict__ ie,
                          float4* __restrict__ emb, float4* __restrict__ acc,
                          long nu4, long ni4) {
    long total = nu4 + ni4;
    long stride = (long)gridDim.x * blockDim.x;
    for (long i = (long)blockIdx.x * blockDim.x + threadIdx.x; i < total; i += stride) {
        float4 v = (i < nu4) ? ue[i] : ie[i - nu4];
        emb[i] = v;
        acc[i] = v;
    }
}

__global__ void lgcn_spmm_atomic(const float* __restrict__ vals, const int* __restrict__ rows,
                                 const int* __restrict__ cols, const float* __restrict__ x,
                                 float* __restrict__ y, int ne) {
    long gid = (long)blockIdx.x * blockDim.x + threadIdx.x;
    int e = (int)(gid >> 6);
    int lane = (int)(gid & 63);
    if (e >= ne) return;
    float xv = x[(size_t)cols[e] * EMB + lane];
    atomicAdd(&y[(size_t)rows[e] * EMB + lane], vals[e] * xv);
}

__global__ void lgcn_acc(const float4* __restrict__ src, float4* __restrict__ acc,
                         long n4, float scale) {
    long stride = (long)gridDim.x * blockDim.x;
    for (long i = (long)blockIdx.x * blockDim.x + threadIdx.x; i < n4; i += stride) {
        float4 a = acc[i];
        float4 s = src[i];
        a.x = (a.x + s.x) * scale;
        a.y = (a.y + s.y) * scale;
        a.z = (a.z + s.z) * scale;
        a.w = (a.w + s.w) * scale;
        acc[i] = a;
    }
}

extern "C" void kernel_launch(void* const* d_in, const int* in_sizes, int n_in,
                              void* d_out, int out_size, void* d_ws, size_t ws_size,
                              hipStream_t stream) {
    const float* ue   = (const float*)d_in[0];
    const float* ie   = (const float*)d_in[1];
    const float* vals = (const float*)d_in[2];
    const int*   rows = (const int*)d_in[3];
    const int*   cols = (const int*)d_in[4];

    const int nu = in_sizes[0] / EMB;
    const int ni = in_sizes[1] / EMB;
    const int ne = in_sizes[2];
    const long n = (long)nu + ni;
    const int nbuck = (int)((n + BROWS - 1) >> BSH);
    const size_t hbuf_bytes = (size_t)n * EMB * sizeof(__half);

    float* acc = (float*)d_out;

    // workspace carve
    char* p = (char*)d_ws;
    __half* xh0 = (__half*)p;              p += hbuf_bytes;
    __half* xh1 = (__half*)p;              p += hbuf_bytes;
    __half* xh2 = (__half*)p;              p += hbuf_bytes;
    unsigned long long* breg = (unsigned long long*)p;  p += (size_t)ne * 8;
    PEdge* pe   = (PEdge*)p;               p += (size_t)ne * sizeof(PEdge);
    int*   row_start = (int*)p;            p += (size_t)(n + 1) * sizeof(int);
    int*   bhist = (int*)p;                p += (size_t)nbuck * sizeof(int);
    int*   bstart = (int*)p;               p += (size_t)nbuck * sizeof(int);
    int*   bcursor = (int*)p;              p += (size_t)nbuck * sizeof(int);
    size_t needed = (size_t)(p - (char*)d_ws);

    const long nu4 = (long)nu * (EMB / 4);
    const long ni4 = (long)ni * (EMB / 4);

    if (needed <= ws_size && nbuck <= NBMAX) {
        // ---- 1) bucket CSR build ----
        (void)hipMemsetAsync(bhist, 0, (size_t)nbuck * sizeof(int), stream);
        k_bhist<<<256, 256, 0, stream>>>(rows, bhist, ne, nbuck);
        k_bscan<<<1, 256, 0, stream>>>(bhist, bstart, bcursor, nbuck);
        k_bscatter<<<2048, 256, 0, stream>>>(rows, cols, vals, bcursor, breg, ne);
        k_bfinal<<<nbuck, 256, 0, stream>>>(breg, bstart, pe, row_start,
                                            (int)n, ne, nbuck);

        // ---- 2) fp16 buffers: defensive zero (call-invariance) + input cvt ----
        (void)hipMemsetAsync(xh0, 0, hbuf_bytes * 3, stream);
        k_cvt<<<2048, 256, 0, stream>>>((const float4*)ue, (const float4*)ie,
                                        (__half2*)xh0, nu4, ni4);

        // ---- 3) 3 SpMM layers; acc deferred entirely to the last kernel ----
        int blocks = (int)((n * 64 + 255) / 256);
        k_spmm_mid<<<blocks, 256, 0, stream>>>(row_start, pe, xh0, xh1, (int)n);
        k_spmm_mid<<<blocks, 256, 0, stream>>>(row_start, pe, xh1, xh2, (int)n);
        k_spmm_last<<<blocks, 256, 0, stream>>>(row_start, pe, xh2, xh1, ue, ie, nu,
                                                acc, (int)n);
    } else {
        // ---- fallback: R1 atomic path (fp32) ----
        const size_t buf_bytes = (size_t)n * EMB * sizeof(float);
        float* buf0 = (float*)d_ws;
        float* buf1 = (float*)((char*)d_ws + buf_bytes);
        const long n4 = n * (EMB / 4);
        lgcn_init<<<2048, 256, 0, stream>>>((const float4*)ue, (const float4*)ie,
                                            (float4*)buf0, (float4*)acc, nu4, ni4);
        float* cur = buf0;
        float* nxt = buf1;
        for (int l = 0; l < 3; ++l) {
            (void)hipMemsetAsync(nxt, 0, buf_bytes, stream);
            long threads = (long)ne * 64;
            int blk = (int)((threads + 255) / 256);
            lgcn_spmm_atomic<<<blk, 256, 0, stream>>>(vals, rows, cols, cur, nxt, ne);
            float scale = (l == 2) ? 0.25f : 1.0f;
            lgcn_acc<<<2048, 256, 0, stream>>>((const float4*)nxt, (float4*)acc, n4, scale);
            float* t = cur; cur = nxt; nxt = t;
        }
    }
}

// Round 13
// 779.264 us; speedup vs baseline: 1.2689x; 1.2689x over previous
//
#include <hip/hip_runtime.h>
#include <hip/hip_fp16.h>

#define EMB 64
#define SCAN_TPB 256
#define SCAN_EPT 8
#define SCAN_ELEMS (SCAN_TPB * SCAN_EPT)  // 2048

// Packed edge: (col << 13) | q, where val = q / 81920.0  (val in [0,0.1) per spec)
typedef unsigned int PEdge;
#define VAL_SCALE 81920.0f
#define VAL_INV   (1.0f / 81920.0f)

// Shard key: cursor/record line granule (16 rows) -> one XCD owns each line.
__device__ __forceinline__ int row_shard(int r) { return (r >> 4) & 7; }

template <typename T>
__device__ __forceinline__ T ntload(const T* p) { return __builtin_nontemporal_load(p); }

// ---------- convert fp32 concat(ue,ie) -> fp16 x buffer ----------
__global__ void k_cvt(const float4* __restrict__ ue, const float4* __restrict__ ie,
                      __half2* __restrict__ xh2, long nu4, long ni4) {
    long total = nu4 + ni4;  // units of 4 floats
    long stride = (long)gridDim.x * blockDim.x;
    for (long i = (long)blockIdx.x * blockDim.x + threadIdx.x; i < total; i += stride) {
        float4 v = (i < nu4) ? ue[i] : ie[i - nu4];
        xh2[i * 2]     = __floats2half2_rn(v.x, v.y);
        xh2[i * 2 + 1] = __floats2half2_rn(v.z, v.w);
    }
}

// ---------- CSR build (XCD-sharded; nt streaming reads) ----------
__global__ void k_hist(const int* __restrict__ rows, int* __restrict__ cnt, int ne) {
    int g  = blockIdx.x & 7;
    int lt = (blockIdx.x >> 3) * blockDim.x + threadIdx.x;
    int gs = (gridDim.x >> 3) * blockDim.x;
    for (int e = lt; e < ne; e += gs) {
        int r = ntload(rows + e);
        if (row_shard(r) == g) atomicAdd(&cnt[r], 1);
    }
}

__global__ void k_scatter(const int* __restrict__ rows, const int* __restrict__ cols,
                          const float* __restrict__ vals, int* __restrict__ cursor,
                          PEdge* __restrict__ pe, int ne) {
    int g  = blockIdx.x & 7;
    int lt = (blockIdx.x >> 3) * blockDim.x + threadIdx.x;
    int gs = (gridDim.x >> 3) * blockDim.x;
    for (int e = lt; e < ne; e += gs) {
        int r = ntload(rows + e);
        if (row_shard(r) == g) {
            int p = atomicAdd(&cursor[r], 1);
            unsigned q = (unsigned)(ntload(vals + e) * VAL_SCALE + 0.5f);
            if (q > 8191u) q = 8191u;
            pe[p] = ((unsigned)ntload(cols + e) << 13) | q;
        }
    }
}

__global__ void k_scan1(const int* __restrict__ in, int* __restrict__ excl,
                        int* __restrict__ bsums, int n) {
    __shared__ int sh[SCAN_TPB];
    int t = threadIdx.x;
    int base = blockIdx.x * SCAN_ELEMS + t * SCAN_EPT;
    int v[SCAN_EPT];
    int ts = 0;
#pragma unroll
    for (int k = 0; k < SCAN_EPT; ++k) {
        v[k] = (base + k < n) ? in[base + k] : 0;
        ts += v[k];
    }
    sh[t] = ts;
    __syncthreads();
    for (int off = 1; off < SCAN_TPB; off <<= 1) {
        int x = (t >= off) ? sh[t - off] : 0;
        __syncthreads();
        sh[t] += x;
        __syncthreads();
    }
    int run = sh[t] - ts;
#pragma unroll
    for (int k = 0; k < SCAN_EPT; ++k) {
        if (base + k < n) excl[base + k] = run;
        run += v[k];
    }
    if (t == SCAN_TPB - 1) bsums[blockIdx.x] = sh[t];
}

__global__ void k_scan2(const int* __restrict__ bsums, int* __restrict__ bexcl, int nb) {
    __shared__ int sh[SCAN_TPB];
    int t = threadIdx.x;
    int ts = (t < nb) ? bsums[t] : 0;
    sh[t] = ts;
    __syncthreads();
    for (int off = 1; off < SCAN_TPB; off <<= 1) {
        int x = (t >= off) ? sh[t - off] : 0;
        __syncthreads();
        sh[t] += x;
        __syncthreads();
    }
    if (t < nb) bexcl[t] = sh[t] - ts;
}

__global__ void k_scan3(int* __restrict__ row_start, int* __restrict__ cursor,
                        const int* __restrict__ bexcl, int n, int ne) {
    int base = blockIdx.x * SCAN_ELEMS + threadIdx.x * SCAN_EPT;
    int off = bexcl[blockIdx.x];
#pragma unroll
    for (int k = 0; k < SCAN_EPT; ++k) {
        if (base + k < n) {
            int v = row_start[base + k] + off;
            row_start[base + k] = v;
            cursor[base + k] = v;
        }
    }
    if (blockIdx.x == 0 && threadIdx.x == 0) row_start[n] = ne;
}

// ---------- SpMM mid layer: cached pe reads; pad slots reuse slot-0 (L1-hot) ----------
__global__ void k_spmm_mid(const int* __restrict__ row_start, const PEdge* __restrict__ pe,
                           const __half* __restrict__ x, __half* __restrict__ nxt, int n) {
    int wid = (int)(((long)blockIdx.x * blockDim.x + threadIdx.x) >> 6);
    int lane = threadIdx.x & 63;
    if (wid >= n) return;
    int s = row_start[wid];
    int e = row_start[wid + 1];
    float sum = 0.f;
    for (int j = s; j < e; j += 8) {
        int   cc[8];
        float vv[8];
#pragma unroll
        for (int k = 0; k < 8; ++k) {
            int jj = j + k;
            bool ok = jj < e;
            unsigned u = pe[ok ? jj : j];      // pad -> slot 0 of THIS block (L1-hot)
            cc[k] = (int)(u >> 13);
            vv[k] = ok ? (float)(u & 8191u) * VAL_INV : 0.f;
        }
        float xs[8];
#pragma unroll
        for (int k = 0; k < 8; ++k)
            xs[k] = __half2float(x[(size_t)cc[k] * EMB + lane]);
#pragma unroll
        for (int k = 0; k < 8; ++k) sum += vv[k] * xs[k];
    }
    size_t o = (size_t)wid * EMB + lane;
    short hs = __half_as_short(__float2half(sum));
    __builtin_nontemporal_store(hs, (short*)nxt + o);
}

// ---------- SpMM last layer: gather from x2 (=e2), combine all 4 layers ----------
__global__ void k_spmm_last(const int* __restrict__ row_start, const PEdge* __restrict__ pe,
                            const __half* __restrict__ x2, const __half* __restrict__ xh1,
                            const float* __restrict__ ue, const float* __restrict__ ie, int nu,
                            float* __restrict__ acc, int n) {
    int wid = (int)(((long)blockIdx.x * blockDim.x + threadIdx.x) >> 6);
    int lane = threadIdx.x & 63;
    if (wid >= n) return;
    int s = row_start[wid];
    int e = row_start[wid + 1];
    float sum = 0.f;
    for (int j = s; j < e; j += 8) {
        int   cc[8];
        float vv[8];
#pragma unroll
        for (int k = 0; k < 8; ++k) {
            int jj = j + k;
            bool ok = jj < e;
            unsigned u = pe[ok ? jj : j];
            cc[k] = (int)(u >> 13);
            vv[k] = ok ? (float)(u & 8191u) * VAL_INV : 0.f;
        }
        float xs[8];
#pragma unroll
        for (int k = 0; k < 8; ++k)
            xs[k] = __half2float(x2[(size_t)cc[k] * EMB + lane]);
#pragma unroll
        for (int k = 0; k < 8; ++k) sum += vv[k] * xs[k];
    }
    size_t o = (size_t)wid * EMB + lane;
    const float* p = (wid < nu) ? (ue + (size_t)wid * EMB) : (ie + (size_t)(wid - nu) * EMB);
    float e0 = p[lane];
    float e1 = __half2float(xh1[o]);
    float e2 = __half2float(x2[o]);
    float r = (e0 + e1 + e2 + sum) * 0.25f;
    __builtin_nontemporal_store(r, acc + o);
}

// ---------- fallback (R1 atomic path, fp32) ----------
__global__ void lgcn_init(const float4* __restrict__ ue, const float4* __restrict__ ie,
                          float4* __restrict__ emb, float4* __restrict__ acc,
                          long nu4, long ni4) {
    long total = nu4 + ni4;
    long stride = (long)gridDim.x * blockDim.x;
    for (long i = (long)blockIdx.x * blockDim.x + threadIdx.x; i < total; i += stride) {
        float4 v = (i < nu4) ? ue[i] : ie[i - nu4];
        emb[i] = v;
        acc[i] = v;
    }
}

__global__ void lgcn_spmm_atomic(const float* __restrict__ vals, const int* __restrict__ rows,
                                 const int* __restrict__ cols, const float* __restrict__ x,
                                 float* __restrict__ y, int ne) {
    long gid = (long)blockIdx.x * blockDim.x + threadIdx.x;
    int e = (int)(gid >> 6);
    int lane = (int)(gid & 63);
    if (e >= ne) return;
    float xv = x[(size_t)cols[e] * EMB + lane];
    atomicAdd(&y[(size_t)rows[e] * EMB + lane], vals[e] * xv);
}

__global__ void lgcn_acc(const float4* __restrict__ src, float4* __restrict__ acc,
                         long n4, float scale) {
    long stride = (long)gridDim.x * blockDim.x;
    for (long i = (long)blockIdx.x * blockDim.x + threadIdx.x; i < n4; i += stride) {
        float4 a = acc[i];
        float4 s = src[i];
        a.x = (a.x + s.x) * scale;
        a.y = (a.y + s.y) * scale;
        a.z = (a.z + s.z) * scale;
        a.w = (a.w + s.w) * scale;
        acc[i] = a;
    }
}

extern "C" void kernel_launch(void* const* d_in, const int* in_sizes, int n_in,
                              void* d_out, int out_size, void* d_ws, size_t ws_size,
                              hipStream_t stream) {
    const float* ue   = (const float*)d_in[0];
    const float* ie   = (const float*)d_in[1];
    const float* vals = (const float*)d_in[2];
    const int*   rows = (const int*)d_in[3];
    const int*   cols = (const int*)d_in[4];

    const int nu = in_sizes[0] / EMB;
    const int ni = in_sizes[1] / EMB;
    const int ne = in_sizes[2];
    const long n = (long)nu + ni;
    const size_t hbuf_bytes = (size_t)n * EMB * sizeof(__half);

    float* acc = (float*)d_out;

    // workspace carve
    char* p = (char*)d_ws;
    __half* xh0 = (__half*)p;    p += hbuf_bytes;
    __half* xh1 = (__half*)p;    p += hbuf_bytes;
    __half* xh2 = (__half*)p;    p += hbuf_bytes;
    PEdge* pe   = (PEdge*)p;     p += (size_t)ne * sizeof(PEdge);
    int*   row_start = (int*)p;  p += (size_t)(n + 1) * sizeof(int);
    int*   cursor = (int*)p;     p += (size_t)n * sizeof(int);
    int nb = (int)((n + SCAN_ELEMS - 1) / SCAN_ELEMS);
    int*   bsums = (int*)p;      p += (size_t)nb * sizeof(int);
    int*   bexcl = (int*)p;      p += (size_t)nb * sizeof(int);
    size_t needed = (size_t)(p - (char*)d_ws);

    const long nu4 = (long)nu * (EMB / 4);
    const long ni4 = (long)ni * (EMB / 4);

    if (needed <= ws_size && nb <= SCAN_TPB) {
        // ---- 1) CSR build (XCD-sharded hist + scatter, nt streaming reads) ----
        (void)hipMemsetAsync(cursor, 0, (size_t)n * sizeof(int), stream);
        k_hist<<<2048, 256, 0, stream>>>(rows, cursor, ne);
        k_scan1<<<nb, SCAN_TPB, 0, stream>>>(cursor, row_start, bsums, (int)n);
        k_scan2<<<1, SCAN_TPB, 0, stream>>>(bsums, bexcl, nb);
        k_scan3<<<nb, SCAN_TPB, 0, stream>>>(row_start, cursor, bexcl, (int)n, ne);
        k_scatter<<<2048, 256, 0, stream>>>(rows, cols, vals, cursor, pe, ne);

        // ---- 2) fp16 buffers: defensive zero (call-invariance) + input cvt ----
        (void)hipMemsetAsync(xh0, 0, hbuf_bytes * 3, stream);
        k_cvt<<<2048, 256, 0, stream>>>((const float4*)ue, (const float4*)ie,
                                        (__half2*)xh0, nu4, ni4);

        // ---- 3) 3 SpMM layers; acc deferred entirely to the last kernel ----
        int blocks = (int)((n * 64 + 255) / 256);
        k_spmm_mid<<<blocks, 256, 0, stream>>>(row_start, pe, xh0, xh1, (int)n);
        k_spmm_mid<<<blocks, 256, 0, stream>>>(row_start, pe, xh1, xh2, (int)n);
        k_spmm_last<<<blocks, 256, 0, stream>>>(row_start, pe, xh2, xh1, ue, ie, nu,
                                                acc, (int)n);
    } else {
        // ---- fallback: R1 atomic path (fp32) ----
        const size_t buf_bytes = (size_t)n * EMB * sizeof(float);
        float* buf0 = (float*)d_ws;
        float* buf1 = (float*)((char*)d_ws + buf_bytes);
        const long n4 = n * (EMB / 4);
        lgcn_init<<<2048, 256, 0, stream>>>((const float4*)ue, (const float4*)ie,
                                            (float4*)buf0, (float4*)acc, nu4, ni4);
        float* cur = buf0;
        float* nxt = buf1;
        for (int l = 0; l < 3; ++l) {
            (void)hipMemsetAsync(nxt, 0, buf_bytes, stream);
            long threads = (long)ne * 64;
            int blk = (int)((threads + 255) / 256);
            lgcn_spmm_atomic<<<blk, 256, 0, stream>>>(vals, rows, cols, cur, nxt, ne);
            float scale = (l == 2) ? 0.25f : 1.0f;
            lgcn_acc<<<2048, 256, 0, stream>>>((const float4*)nxt, (float4*)acc, n4, scale);
            float* t = cur; cur = nxt; nxt = t;
        }
    }
}